// Round 10
// baseline (219.614 us; speedup 1.0000x reference)
//
#include <hip/hip_runtime.h>
#include <hip/hip_bf16.h>

// Air3D CNF forward.
//  - traj_pack_kernel: block 0 = batch-independent ODE (RK4-5, h=0.2, cubic Hermite
//    dense output onto the 101-grid); blocks 1.. = weight packing into MFMA frag order
//  - decoder_kernel: MTILE=64, 512 thr (8 waves as 2m x 4n), operand-swapped MFMA
//    (D=Y^T), double-buffered Ha/Hb (ONE barrier/layer). Per wave: acc[2][8] (64 VGPR)
//    + xf[2] + wf[8] ~= 104 live VGPR -> no spill, no nt-half re-read. LDS xf traffic
//    4x lower than the 4mx4n r9 tiling (each wave reads only its 2 m-tiles).
//    HARD-WON: 1024-thr blocks always get VGPR=64 (+scratch spill) from hipcc (r4/r5/r8);
//    (512,2) -> 128 VGPR no-spill (r2/r9). Do not change the launch geometry.
// ws: pw[598016 ushort] = pw0|pw1|pw2|pw3, then traj[1010 float]

#define B_TOTAL 65536
#define MTILE   64

typedef short bf16x8 __attribute__((ext_vector_type(8)));
typedef float f32x4  __attribute__((ext_vector_type(4)));

// tanh = 1 - 2/(e^{2x}+1) = 1 - 2*rcp(exp2(x*2*log2e)+1). Exact at +-inf, no clamp.
__device__ __forceinline__ float tanh_fast(float x) {
  float e = __builtin_amdgcn_exp2f(x * 2.88539008178f);
  return fmaf(-2.0f, __builtin_amdgcn_rcpf(e + 1.0f), 1.0f);
}

__device__ __forceinline__ unsigned short f2bf(float f) {
  union { float f; unsigned u; } v; v.f = f;
  unsigned r = v.u + 0x7FFFu + ((v.u >> 16) & 1u);   // RNE to bf16
  return (unsigned short)(r >> 16);
}

__device__ __forceinline__ unsigned pack2bf(float a, float b) {
  union { __hip_bfloat162 h; unsigned u; } c;
  c.h = __float22bfloat162_rn(make_float2(a, b));
  return c.u;
}

// ---------------- fused traj (block 0) + weight packing (blocks 1..4672) ----------------
// pack: frag f = ntile*KC + kc; lane l slot j -> W[kc*32 + (l>>4)*8 + j][ntile*16 + (l&15)]
__global__ __launch_bounds__(128) void traj_pack_kernel(
    const float* __restrict__ w0, const float* __restrict__ b0,
    const float* __restrict__ w1, const float* __restrict__ b1,
    const float* __restrict__ w2, const float* __restrict__ b2,
    const float* __restrict__ dw0, const float* __restrict__ dw1,
    const float* __restrict__ dw2, const float* __restrict__ dw3,
    unsigned short* __restrict__ pw, float* __restrict__ traj) {
  if (blockIdx.x != 0) {
    // -------- pack path --------
    int idx = (int)(blockIdx.x - 1) * 128 + threadIdx.x;   // 0..598015
    const float* w; int K_real, N_real, KC, base;
    if (idx < 65536)       { w = dw0; K_real = 106; N_real = 512; KC = 4;  base = 0; }
    else if (idx < 327680) { w = dw1; K_real = 512; N_real = 512; KC = 16; base = 65536; }
    else if (idx < 589824) { w = dw2; K_real = 512; N_real = 512; KC = 16; base = 327680; }
    else                   { w = dw3; K_real = 512; N_real = 1;   KC = 16; base = 589824; }
    int r = idx - base;
    int j = r & 7, l = (r >> 3) & 63, rest = r >> 9;
    int kc = rest % KC, ntg = rest / KC;
    int k = kc * 32 + ((l >> 4) << 3) + j;
    int n = ntg * 16 + (l & 15);
    float v = (k < K_real && n < N_real) ? w[k * N_real + n] : 0.0f;
    pw[idx] = f2bf(v);
    return;
  }

  // -------- trajectory path: 128 threads, fp32, RK4 h=0.2 (5 steps) --------
  __shared__ __align__(16) float ain[16];
  __shared__ __align__(16) float h1[128];
  __shared__ __align__(16) float h2[128];
  __shared__ __align__(16) float kst[16];
  const int tid = threadIdx.x;
  const float H = 0.2f;

  float w0c[11], w1c[128];
  float b0j = b0[tid], b1j = b1[tid];
#pragma unroll
  for (int i = 0; i < 11; i++) w0c[i] = w0[i * 128 + tid];
#pragma unroll
  for (int i = 0; i < 128; i++) w1c[i] = w1[i * 128 + tid];

  const int kk = tid >> 3, p = tid & 7;   // L3: 8 threads per output, 10 outputs -> tid<80
  float w2r[16];
  float b2k = 0.0f;
  if (tid < 80) {
#pragma unroll
    for (int ii = 0; ii < 16; ii++) w2r[ii] = w2[(p * 16 + ii) * 10 + kk];
    if (p == 0) b2k = b2[kk];
  }

  float a_j = 0.0f;
  float k1j = 0.f, k2j = 0.f, k3j = 0.f;
  float a_ps = 0.f, k1p = 0.f;   // previous step start-state and its f, for Hermite

  auto eval = [&](float tval) {
    // L1: 11 -> 128
    float pre = b0j;
#pragma unroll
    for (int i = 0; i < 10; i++) pre = fmaf(ain[i], w0c[i], pre);
    pre = fmaf(tval, w0c[10], pre);
    h1[tid] = tanh_fast(pre);
    __syncthreads();
    // L2: 128 -> 128
    float ac0 = 0.f, ac1 = 0.f, ac2 = 0.f, ac3 = 0.f;
    const float4* h1v = (const float4*)h1;
#pragma unroll
    for (int i = 0; i < 32; i++) {
      float4 hv = h1v[i];
      ac0 = fmaf(hv.x, w1c[4 * i + 0], ac0);
      ac1 = fmaf(hv.y, w1c[4 * i + 1], ac1);
      ac2 = fmaf(hv.z, w1c[4 * i + 2], ac2);
      ac3 = fmaf(hv.w, w1c[4 * i + 3], ac3);
    }
    h2[tid] = tanh_fast(b1j + ((ac0 + ac1) + (ac2 + ac3)));
    __syncthreads();
    // L3: 128 -> 10
    if (tid < 80) {
      float part = 0.f;
#pragma unroll
      for (int ii = 0; ii < 16; ii++) part = fmaf(h2[p * 16 + ii], w2r[ii], part);
      part += __shfl_xor(part, 1);
      part += __shfl_xor(part, 2);
      part += __shfl_xor(part, 4);
      if (p == 0) kst[kk] = part + b2k;
    }
    __syncthreads();
  };

  // cubic Hermite dense output: 19 interior grid points of one h-interval (tid<10)
  auto dense = [&](int g, float a0, float f0, float a1, float f1) {
    for (int m = 1; m <= 19; m++) {
      float th = 0.05f * (float)m;
      float om = 1.0f - th;
      float h00 = (1.0f + 2.0f * th) * om * om;
      float h10 = th * om * om * H;
      float h01 = th * th * (3.0f - 2.0f * th);
      float h11 = th * th * (th - 1.0f) * H;
      traj[(g + m) * 10 + tid] = h00 * a0 + h10 * f0 + h01 * a1 + h11 * f1;
    }
  };

  for (int s = 0; s < 5; s++) {
    float t0 = (float)s * H;
    if (tid < 10) ain[tid] = a_j;
    __syncthreads();
    eval(t0);                              // k1
    if (tid < 10) {
      k1j = kst[tid];
      traj[(20 * s) * 10 + tid] = a_j;     // exact grid value at step start
      if (s > 0) dense(20 * (s - 1), a_ps, k1p, a_j, k1j);
      a_ps = a_j; k1p = k1j;
      ain[tid] = fmaf(0.1f, k1j, a_j);
    }
    __syncthreads();
    eval(t0 + 0.1f);                       // k2
    if (tid < 10) { k2j = kst[tid]; ain[tid] = fmaf(0.1f, k2j, a_j); }
    __syncthreads();
    eval(t0 + 0.1f);                       // k3
    if (tid < 10) { k3j = kst[tid]; ain[tid] = fmaf(0.2f, k3j, a_j); }
    __syncthreads();
    eval(t0 + 0.2f);                       // k4
    if (tid < 10) {
      float k4j = kst[tid];
      a_j = a_j + (H / 6.0f) * (k1j + 2.0f * k2j + 2.0f * k3j + k4j);
    }
  }
  // final: f(1.0, a_5) for the last interval's Hermite + grid 100
  if (tid < 10) ain[tid] = a_j;
  __syncthreads();
  eval(1.0f);
  if (tid < 10) {
    float f1 = kst[tid];
    dense(80, a_ps, k1p, a_j, f1);
    traj[100 * 10 + tid] = a_j;
  }
}

// ---------------- decoder layer: operand-swapped (A=W^T frags, B=X^T), dbuf ----------------
// Wave (mg,ng): rows mg*32..+31 (2 m-tiles), cols ng*128..+127 (8 n-tiles).
// acc[2][8] + xf[2] + wf[8] fits the 128-VGPR cap in ONE pass (no nt-halves).
template <int KC, bool ACT>
__device__ __forceinline__ void layer(const char* src, char* dst,
                                      const unsigned short* __restrict__ pw,
                                      const float* __restrict__ bias,
                                      int mg, int ng, int lane) {
  const int g16 = (lane >> 4) << 4;
  const int swz = (lane & 7) << 4;
  const int rbase = (mg * 32 + (lane & 15)) * 1024;       // mt adds 16*1024
  const unsigned short* pwB = pw + (ng * 8 * KC * 64 + lane) * 8;
  const int g4 = (lane >> 4) << 2;

  f32x4 acc[2][8];
#pragma unroll
  for (int a = 0; a < 2; a++)
#pragma unroll
    for (int b = 0; b < 8; b++) acc[a][b] = f32x4{0.f, 0.f, 0.f, 0.f};

#pragma unroll
  for (int kc = 0; kc < KC; kc++) {
    bf16x8 xf[2];
#pragma unroll
    for (int mt = 0; mt < 2; mt++)
      xf[mt] = *(const bf16x8*)(src + rbase + mt * 16384 + ((kc * 64 + g16) ^ swz));
    bf16x8 wf[8];
#pragma unroll
    for (int nt = 0; nt < 8; nt++)
      wf[nt] = *(const bf16x8*)(pwB + (nt * KC + kc) * 512);
#pragma unroll
    for (int mt = 0; mt < 2; mt++)
#pragma unroll
      for (int nt = 0; nt < 8; nt++)
        acc[mt][nt] = __builtin_amdgcn_mfma_f32_16x16x32_bf16(wf[nt], xf[mt], acc[mt][nt], 0, 0, 0);
  }

  // epilogue: bias + tanh -> bf16 -> dst (D: col=lane&15 = sample row, n = nc+reg)
#pragma unroll
  for (int nt = 0; nt < 8; nt++) {
    int nc = ng * 128 + nt * 16 + g4;
    const float4 bv = *(const float4*)(bias + nc);
#pragma unroll
    for (int mt = 0; mt < 2; mt++) {
      float v0 = acc[mt][nt][0] + bv.x, v1 = acc[mt][nt][1] + bv.y;
      float v2 = acc[mt][nt][2] + bv.z, v3 = acc[mt][nt][3] + bv.w;
      if (ACT) { v0 = tanh_fast(v0); v1 = tanh_fast(v1); v2 = tanh_fast(v2); v3 = tanh_fast(v3); }
      *(uint2*)(dst + rbase + mt * 16384 + ((nc * 2) ^ swz)) =
          make_uint2(pack2bf(v0, v1), pack2bf(v2, v3));
    }
  }
  __syncthreads();
}

__global__ __launch_bounds__(512, 2) void decoder_kernel(
    const float* __restrict__ x, const float* __restrict__ tauv,
    const unsigned short* __restrict__ pw0, const float* __restrict__ db0,
    const unsigned short* __restrict__ pw1, const float* __restrict__ db1,
    const unsigned short* __restrict__ pw2, const float* __restrict__ db2,
    const unsigned short* __restrict__ pw3, const float* __restrict__ db3,
    const float* __restrict__ traj, float* __restrict__ out) {
  __shared__ char Ha[65536];                         // [64 rows][1024B], XOR-swizzled
  __shared__ char Hb[65536];
  __shared__ float ubuf[64];
  const int tid = threadIdx.x;
  const int lane = tid & 63;
  const int wave = tid >> 6;
  const int row0 = blockIdx.x * MTILE;

  // ---- stage Fourier features into Ha: r = tid>>3 (64 rows), 12 features per thread ----
  {
    int r = tid >> 3, fg = tid & 7;
    const float* xr = x + (row0 + r) * 3;
    float xr0 = xr[0], xr1 = xr[1], xr2 = xr[2];
    int swz = (r & 7) << 4;
    char* rp = Ha + r * 1024;
    float vals[12];
#pragma unroll
    for (int ff = 0; ff < 12; ff++) {
      int f = fg * 12 + ff;
      int d = f >> 5, s = f & 31;
      float xv = (d == 0) ? xr0 : ((d == 1) ? xr1 : xr2);
      float freq = 1.0f + 0.6f * (float)(s & 15);
      float rev = xv * freq;
      rev = rev - floorf(rev);
      vals[ff] = (s < 16) ? __builtin_amdgcn_sinf(rev) : __builtin_amdgcn_cosf(rev);
    }
#pragma unroll
    for (int c = 0; c < 3; c++)
      *(uint2*)(rp + ((fg * 24 + c * 8) ^ swz)) =
          make_uint2(pack2bf(vals[4 * c], vals[4 * c + 1]), pack2bf(vals[4 * c + 2], vals[4 * c + 3]));
  }
  // ---- stage alpha(tau) + zero pad (cols 96..127) ----
  if (tid < 64) {
    int i = row0 + tid;
    float tv = tauv[i];
    int id0 = (int)floorf(tv * 100.0f);
    id0 = min(max(id0, 0), 99);
    float ratio = tv * 100.0f - (float)id0;
    float al[10];
#pragma unroll
    for (int j = 0; j < 10; j++) {
      float a0 = traj[id0 * 10 + j], a1 = traj[id0 * 10 + 10 + j];
      al[j] = fmaf(ratio, a1 - a0, a0);
    }
    int swz = (tid & 7) << 4;
    char* rp = Ha + tid * 1024;
    *(uint4*)(rp + (192 ^ swz)) = make_uint4(pack2bf(al[0], al[1]), pack2bf(al[2], al[3]),
                                             pack2bf(al[4], al[5]), pack2bf(al[6], al[7]));
    *(uint4*)(rp + (208 ^ swz)) = make_uint4(pack2bf(al[8], al[9]), 0u, 0u, 0u);
    *(uint4*)(rp + (224 ^ swz)) = make_uint4(0u, 0u, 0u, 0u);
    *(uint4*)(rp + (240 ^ swz)) = make_uint4(0u, 0u, 0u, 0u);
  }
  __syncthreads();

  const int mg = wave >> 2;                          // 2 m-groups x 4 n-groups
  const int ng = wave & 3;
  layer<4, true>(Ha, Hb, pw0, db0, mg, ng, lane);    // 106(pad128) -> 512
  layer<16, true>(Hb, Ha, pw1, db1, mg, ng, lane);   // 512 -> 512
  layer<16, true>(Ha, Hb, pw2, db2, mg, ng, lane);   // 512 -> 512

  // ---- L3: 512 -> 1, waves 0..3 each own a 16-row m-tile (reads Hb) ----
  if (wave < 4) {
    f32x4 acc = {0.f, 0.f, 0.f, 0.f};
    int rbase = (wave * 16 + (lane & 15)) * 1024;
    int swz = (lane & 7) << 4;
    int g16 = (lane >> 4) << 4;
#pragma unroll
    for (int kcv = 0; kcv < 16; kcv++) {
      bf16x8 xfv = *(const bf16x8*)(Hb + rbase + ((kcv * 64 + g16) ^ swz));
      bf16x8 wfv = *(const bf16x8*)(pw3 + (kcv * 64 + lane) * 8);
      acc = __builtin_amdgcn_mfma_f32_16x16x32_bf16(wfv, xfv, acc, 0, 0, 0);
    }
    if (lane < 16) ubuf[wave * 16 + lane] = acc[0];  // n==0 lives in lanes 0..15, reg 0
  }
  __syncthreads();

  // ---- epilogue: out = lx + tau * (u + b3) ----
  if (tid < 64) {
    int i = row0 + tid;
    float x0 = x[i * 3], x1 = x[i * 3 + 1];
    float tv = tauv[i];
    float u = ubuf[tid] + db3[0];
    out[i] = sqrtf(x0 * x0 + x1 * x1) - 0.25f + tv * u;
  }
}

// ---------------- launch ----------------
extern "C" void kernel_launch(void* const* d_in, const int* in_sizes, int n_in,
                              void* d_out, int out_size, void* d_ws, size_t ws_size,
                              hipStream_t stream) {
  const float* x    = (const float*)d_in[0];
  const float* tauv = (const float*)d_in[1];
  const float* dw0  = (const float*)d_in[2];
  const float* db0  = (const float*)d_in[3];
  const float* dw1  = (const float*)d_in[4];
  const float* db1  = (const float*)d_in[5];
  const float* dw2  = (const float*)d_in[6];
  const float* db2  = (const float*)d_in[7];
  const float* dw3  = (const float*)d_in[8];
  const float* db3  = (const float*)d_in[9];
  const float* pnw0 = (const float*)d_in[10];
  const float* pnb0 = (const float*)d_in[11];
  const float* pnw1 = (const float*)d_in[12];
  const float* pnb1 = (const float*)d_in[13];
  const float* pnw2 = (const float*)d_in[14];
  const float* pnb2 = (const float*)d_in[15];
  float* out = (float*)d_out;

  unsigned short* pw = (unsigned short*)d_ws;
  unsigned short* pw0 = pw;
  unsigned short* pw1 = pw + 65536;
  unsigned short* pw2 = pw + 327680;
  unsigned short* pw3 = pw + 589824;
  float* traj = (float*)(pw + 598016);

  traj_pack_kernel<<<4673, 128, 0, stream>>>(pnw0, pnb0, pnw1, pnb1, pnw2, pnb2,
                                             dw0, dw1, dw2, dw3, pw, traj);
  decoder_kernel<<<B_TOTAL / MTILE, 512, 0, stream>>>(x, tauv, pw0, db0, pw1, db1,
                                                      pw2, db2, pw3, db3, traj, out);
}

// Round 11
// 204.845 us; speedup vs baseline: 1.0721x; 1.0721x over previous
//
#include <hip/hip_runtime.h>
#include <hip/hip_bf16.h>

// Air3D CNF forward.
//  - traj_pack_kernel: block 0 = batch-independent ODE (RK4-5, h=0.2, cubic Hermite
//    dense output onto the 101-grid); blocks 1.. = weight packing into MFMA frag order
//  - decoder_kernel: MTILE=32, 512 thr (8 waves; each owns 32 rows x 64 cols = 2mt x 4nt),
//    operand-swapped MFMA (D=Y^T), double-buffered Ha/Hb (32KB each -> 2 blocks/CU
//    co-resident), explicit 1-ahead A/B fragment pipeline (acc[2][4]=32 VGPR leaves room).
//    HARD-WON: 1024-thr blocks always get VGPR=64 (+scratch spill) from hipcc (r4/r5/r8);
//    (512,2) -> <=128 VGPR no-spill (r2/r9/r10). Do not change the launch geometry.
// ws: pw[598016 ushort] = pw0|pw1|pw2|pw3, then traj[1010 float]

#define B_TOTAL 65536
#define MTILE   32

typedef short bf16x8 __attribute__((ext_vector_type(8)));
typedef float f32x4  __attribute__((ext_vector_type(4)));

// tanh = 1 - 2/(e^{2x}+1) = 1 - 2*rcp(exp2(x*2*log2e)+1). Exact at +-inf, no clamp.
__device__ __forceinline__ float tanh_fast(float x) {
  float e = __builtin_amdgcn_exp2f(x * 2.88539008178f);
  return fmaf(-2.0f, __builtin_amdgcn_rcpf(e + 1.0f), 1.0f);
}

__device__ __forceinline__ unsigned short f2bf(float f) {
  union { float f; unsigned u; } v; v.f = f;
  unsigned r = v.u + 0x7FFFu + ((v.u >> 16) & 1u);   // RNE to bf16
  return (unsigned short)(r >> 16);
}

__device__ __forceinline__ unsigned pack2bf(float a, float b) {
  union { __hip_bfloat162 h; unsigned u; } c;
  c.h = __float22bfloat162_rn(make_float2(a, b));
  return c.u;
}

// ---------------- fused traj (block 0) + weight packing (blocks 1..4672) ----------------
// pack: frag f = ntile*KC + kc; lane l slot j -> W[kc*32 + (l>>4)*8 + j][ntile*16 + (l&15)]
__global__ __launch_bounds__(128) void traj_pack_kernel(
    const float* __restrict__ w0, const float* __restrict__ b0,
    const float* __restrict__ w1, const float* __restrict__ b1,
    const float* __restrict__ w2, const float* __restrict__ b2,
    const float* __restrict__ dw0, const float* __restrict__ dw1,
    const float* __restrict__ dw2, const float* __restrict__ dw3,
    unsigned short* __restrict__ pw, float* __restrict__ traj) {
  if (blockIdx.x != 0) {
    // -------- pack path --------
    int idx = (int)(blockIdx.x - 1) * 128 + threadIdx.x;   // 0..598015
    const float* w; int K_real, N_real, KC, base;
    if (idx < 65536)       { w = dw0; K_real = 106; N_real = 512; KC = 4;  base = 0; }
    else if (idx < 327680) { w = dw1; K_real = 512; N_real = 512; KC = 16; base = 65536; }
    else if (idx < 589824) { w = dw2; K_real = 512; N_real = 512; KC = 16; base = 327680; }
    else                   { w = dw3; K_real = 512; N_real = 1;   KC = 16; base = 589824; }
    int r = idx - base;
    int j = r & 7, l = (r >> 3) & 63, rest = r >> 9;
    int kc = rest % KC, ntg = rest / KC;
    int k = kc * 32 + ((l >> 4) << 3) + j;
    int n = ntg * 16 + (l & 15);
    float v = (k < K_real && n < N_real) ? w[k * N_real + n] : 0.0f;
    pw[idx] = f2bf(v);
    return;
  }

  // -------- trajectory path: 128 threads, fp32, RK4 h=0.2 (5 steps) --------
  __shared__ __align__(16) float ain[16];
  __shared__ __align__(16) float h1[128];
  __shared__ __align__(16) float h2[128];
  __shared__ __align__(16) float kst[16];
  const int tid = threadIdx.x;
  const float H = 0.2f;

  float w0c[11], w1c[128];
  float b0j = b0[tid], b1j = b1[tid];
#pragma unroll
  for (int i = 0; i < 11; i++) w0c[i] = w0[i * 128 + tid];
#pragma unroll
  for (int i = 0; i < 128; i++) w1c[i] = w1[i * 128 + tid];

  const int kk = tid >> 3, p = tid & 7;   // L3: 8 threads per output, 10 outputs -> tid<80
  float w2r[16];
  float b2k = 0.0f;
  if (tid < 80) {
#pragma unroll
    for (int ii = 0; ii < 16; ii++) w2r[ii] = w2[(p * 16 + ii) * 10 + kk];
    if (p == 0) b2k = b2[kk];
  }

  float a_j = 0.0f;
  float k1j = 0.f, k2j = 0.f, k3j = 0.f;
  float a_ps = 0.f, k1p = 0.f;   // previous step start-state and its f, for Hermite

  auto eval = [&](float tval) {
    // L1: 11 -> 128
    float pre = b0j;
#pragma unroll
    for (int i = 0; i < 10; i++) pre = fmaf(ain[i], w0c[i], pre);
    pre = fmaf(tval, w0c[10], pre);
    h1[tid] = tanh_fast(pre);
    __syncthreads();
    // L2: 128 -> 128
    float ac0 = 0.f, ac1 = 0.f, ac2 = 0.f, ac3 = 0.f;
    const float4* h1v = (const float4*)h1;
#pragma unroll
    for (int i = 0; i < 32; i++) {
      float4 hv = h1v[i];
      ac0 = fmaf(hv.x, w1c[4 * i + 0], ac0);
      ac1 = fmaf(hv.y, w1c[4 * i + 1], ac1);
      ac2 = fmaf(hv.z, w1c[4 * i + 2], ac2);
      ac3 = fmaf(hv.w, w1c[4 * i + 3], ac3);
    }
    h2[tid] = tanh_fast(b1j + ((ac0 + ac1) + (ac2 + ac3)));
    __syncthreads();
    // L3: 128 -> 10
    if (tid < 80) {
      float part = 0.f;
#pragma unroll
      for (int ii = 0; ii < 16; ii++) part = fmaf(h2[p * 16 + ii], w2r[ii], part);
      part += __shfl_xor(part, 1);
      part += __shfl_xor(part, 2);
      part += __shfl_xor(part, 4);
      if (p == 0) kst[kk] = part + b2k;
    }
    __syncthreads();
  };

  // cubic Hermite dense output: 19 interior grid points of one h-interval (tid<10)
  auto dense = [&](int g, float a0, float f0, float a1, float f1) {
    for (int m = 1; m <= 19; m++) {
      float th = 0.05f * (float)m;
      float om = 1.0f - th;
      float h00 = (1.0f + 2.0f * th) * om * om;
      float h10 = th * om * om * H;
      float h01 = th * th * (3.0f - 2.0f * th);
      float h11 = th * th * (th - 1.0f) * H;
      traj[(g + m) * 10 + tid] = h00 * a0 + h10 * f0 + h01 * a1 + h11 * f1;
    }
  };

  for (int s = 0; s < 5; s++) {
    float t0 = (float)s * H;
    if (tid < 10) ain[tid] = a_j;
    __syncthreads();
    eval(t0);                              // k1
    if (tid < 10) {
      k1j = kst[tid];
      traj[(20 * s) * 10 + tid] = a_j;     // exact grid value at step start
      if (s > 0) dense(20 * (s - 1), a_ps, k1p, a_j, k1j);
      a_ps = a_j; k1p = k1j;
      ain[tid] = fmaf(0.1f, k1j, a_j);
    }
    __syncthreads();
    eval(t0 + 0.1f);                       // k2
    if (tid < 10) { k2j = kst[tid]; ain[tid] = fmaf(0.1f, k2j, a_j); }
    __syncthreads();
    eval(t0 + 0.1f);                       // k3
    if (tid < 10) { k3j = kst[tid]; ain[tid] = fmaf(0.2f, k3j, a_j); }
    __syncthreads();
    eval(t0 + 0.2f);                       // k4
    if (tid < 10) {
      float k4j = kst[tid];
      a_j = a_j + (H / 6.0f) * (k1j + 2.0f * k2j + 2.0f * k3j + k4j);
    }
  }
  // final: f(1.0, a_5) for the last interval's Hermite + grid 100
  if (tid < 10) ain[tid] = a_j;
  __syncthreads();
  eval(1.0f);
  if (tid < 10) {
    float f1 = kst[tid];
    dense(80, a_ps, k1p, a_j, f1);
    traj[100 * 10 + tid] = a_j;
  }
}

// ---------------- decoder layer: operand-swapped (A=W^T frags, B=X^T), dbuf ----------------
// MTILE=32: wave owns the full 32 rows (2 m-tiles) x its 64-col slice (4 n-tiles).
// acc[2][4]=32 VGPR + A/B pipelined frags (2x(2+4)=48) -> fits 128 cap, one pass.
template <int KC, bool ACT>
__device__ __forceinline__ void layer(const char* src, char* dst,
                                      const unsigned short* __restrict__ pw,
                                      const float* __restrict__ bias,
                                      int wave, int lane) {
  const int g16 = (lane >> 4) << 4;
  const int swz = (lane & 7) << 4;
  const int rbase = (lane & 15) * 1024;             // mt adds 16*1024
  const unsigned short* pwB = pw + ((wave * 4) * KC * 64 + lane) * 8;
  const int g4 = (lane >> 4) << 2;

  f32x4 acc[2][4];
#pragma unroll
  for (int a = 0; a < 2; a++)
#pragma unroll
    for (int b = 0; b < 4; b++) acc[a][b] = f32x4{0.f, 0.f, 0.f, 0.f};

  bf16x8 xfA[2], xfB[2], wfA[4], wfB[4];
  auto loadx = [&](bf16x8* xf, int kc) {
#pragma unroll
    for (int mt = 0; mt < 2; mt++)
      xf[mt] = *(const bf16x8*)(src + rbase + mt * 16384 + ((kc * 64 + g16) ^ swz));
  };
  auto loadw = [&](bf16x8* wf, int kc) {
#pragma unroll
    for (int nt = 0; nt < 4; nt++)
      wf[nt] = *(const bf16x8*)(pwB + (nt * KC + kc) * 512);
  };
  auto mfma8 = [&](const bf16x8* wf, const bf16x8* xf) {
#pragma unroll
    for (int mt = 0; mt < 2; mt++)
#pragma unroll
      for (int nt = 0; nt < 4; nt++)
        acc[mt][nt] = __builtin_amdgcn_mfma_f32_16x16x32_bf16(wf[nt], xf[mt], acc[mt][nt], 0, 0, 0);
  };

  loadx(xfA, 0); loadw(wfA, 0);
#pragma unroll
  for (int kc = 0; kc < KC; kc += 2) {
    if (kc + 1 < KC) { loadx(xfB, kc + 1); loadw(wfB, kc + 1); }
    mfma8(wfA, xfA);
    if (kc + 2 < KC) { loadx(xfA, kc + 2); loadw(wfA, kc + 2); }
    if (kc + 1 < KC) mfma8(wfB, xfB);
  }

  // epilogue: bias + tanh -> bf16 -> dst (D: col=lane&15 = sample row, n = nc+reg)
#pragma unroll
  for (int nt = 0; nt < 4; nt++) {
    int nc = wave * 64 + nt * 16 + g4;
    const float4 bv = *(const float4*)(bias + nc);
#pragma unroll
    for (int mt = 0; mt < 2; mt++) {
      float v0 = acc[mt][nt][0] + bv.x, v1 = acc[mt][nt][1] + bv.y;
      float v2 = acc[mt][nt][2] + bv.z, v3 = acc[mt][nt][3] + bv.w;
      if (ACT) { v0 = tanh_fast(v0); v1 = tanh_fast(v1); v2 = tanh_fast(v2); v3 = tanh_fast(v3); }
      *(uint2*)(dst + rbase + mt * 16384 + ((nc * 2) ^ swz)) =
          make_uint2(pack2bf(v0, v1), pack2bf(v2, v3));
    }
  }
  __syncthreads();
}

__global__ __launch_bounds__(512, 2) void decoder_kernel(
    const float* __restrict__ x, const float* __restrict__ tauv,
    const unsigned short* __restrict__ pw0, const float* __restrict__ db0,
    const unsigned short* __restrict__ pw1, const float* __restrict__ db1,
    const unsigned short* __restrict__ pw2, const float* __restrict__ db2,
    const unsigned short* __restrict__ pw3, const float* __restrict__ db3,
    const float* __restrict__ traj, float* __restrict__ out) {
  __shared__ char Ha[32768];                         // [32 rows][1024B], XOR-swizzled
  __shared__ char Hb[32768];
  __shared__ float ubuf[32];
  const int tid = threadIdx.x;
  const int lane = tid & 63;
  const int wave = tid >> 6;
  const int row0 = blockIdx.x * MTILE;

  // ---- stage Fourier features into Ha: threads 0..255, r = tid>>3 (32 rows) ----
  if (tid < 256) {
    int r = tid >> 3, fg = tid & 7;
    const float* xr = x + (row0 + r) * 3;
    float xr0 = xr[0], xr1 = xr[1], xr2 = xr[2];
    int swz = (r & 7) << 4;
    char* rp = Ha + r * 1024;
    float vals[12];
#pragma unroll
    for (int ff = 0; ff < 12; ff++) {
      int f = fg * 12 + ff;
      int d = f >> 5, s = f & 31;
      float xv = (d == 0) ? xr0 : ((d == 1) ? xr1 : xr2);
      float freq = 1.0f + 0.6f * (float)(s & 15);
      float rev = xv * freq;
      rev = rev - floorf(rev);
      vals[ff] = (s < 16) ? __builtin_amdgcn_sinf(rev) : __builtin_amdgcn_cosf(rev);
    }
#pragma unroll
    for (int c = 0; c < 3; c++)
      *(uint2*)(rp + ((fg * 24 + c * 8) ^ swz)) =
          make_uint2(pack2bf(vals[4 * c], vals[4 * c + 1]), pack2bf(vals[4 * c + 2], vals[4 * c + 3]));
  }
  // ---- stage alpha(tau) + zero pad (cols 96..127) ----
  if (tid < 32) {
    int i = row0 + tid;
    float tv = tauv[i];
    int id0 = (int)floorf(tv * 100.0f);
    id0 = min(max(id0, 0), 99);
    float ratio = tv * 100.0f - (float)id0;
    float al[10];
#pragma unroll
    for (int j = 0; j < 10; j++) {
      float a0 = traj[id0 * 10 + j], a1 = traj[id0 * 10 + 10 + j];
      al[j] = fmaf(ratio, a1 - a0, a0);
    }
    int swz = (tid & 7) << 4;
    char* rp = Ha + tid * 1024;
    *(uint4*)(rp + (192 ^ swz)) = make_uint4(pack2bf(al[0], al[1]), pack2bf(al[2], al[3]),
                                             pack2bf(al[4], al[5]), pack2bf(al[6], al[7]));
    *(uint4*)(rp + (208 ^ swz)) = make_uint4(pack2bf(al[8], al[9]), 0u, 0u, 0u);
    *(uint4*)(rp + (224 ^ swz)) = make_uint4(0u, 0u, 0u, 0u);
    *(uint4*)(rp + (240 ^ swz)) = make_uint4(0u, 0u, 0u, 0u);
  }
  __syncthreads();

  layer<4, true>(Ha, Hb, pw0, db0, wave, lane);      // 106(pad128) -> 512
  layer<16, true>(Hb, Ha, pw1, db1, wave, lane);     // 512 -> 512
  layer<16, true>(Ha, Hb, pw2, db2, wave, lane);     // 512 -> 512

  // ---- L3: 512 -> 1, waves 0..1 each own a 16-row m-tile (reads Hb) ----
  if (wave < 2) {
    f32x4 acc = {0.f, 0.f, 0.f, 0.f};
    int rbase = (wave * 16 + (lane & 15)) * 1024;
    int swz = (lane & 7) << 4;
    int g16 = (lane >> 4) << 4;
#pragma unroll
    for (int kcv = 0; kcv < 16; kcv++) {
      bf16x8 xfv = *(const bf16x8*)(Hb + rbase + ((kcv * 64 + g16) ^ swz));
      bf16x8 wfv = *(const bf16x8*)(pw3 + (kcv * 64 + lane) * 8);
      acc = __builtin_amdgcn_mfma_f32_16x16x32_bf16(wfv, xfv, acc, 0, 0, 0);
    }
    if (lane < 16) ubuf[wave * 16 + lane] = acc[0];  // n==0 lives in lanes 0..15, reg 0
  }
  __syncthreads();

  // ---- epilogue: out = lx + tau * (u + b3) ----
  if (tid < 32) {
    int i = row0 + tid;
    float x0 = x[i * 3], x1 = x[i * 3 + 1];
    float tv = tauv[i];
    float u = ubuf[tid] + db3[0];
    out[i] = sqrtf(x0 * x0 + x1 * x1) - 0.25f + tv * u;
  }
}

// ---------------- launch ----------------
extern "C" void kernel_launch(void* const* d_in, const int* in_sizes, int n_in,
                              void* d_out, int out_size, void* d_ws, size_t ws_size,
                              hipStream_t stream) {
  const float* x    = (const float*)d_in[0];
  const float* tauv = (const float*)d_in[1];
  const float* dw0  = (const float*)d_in[2];
  const float* db0  = (const float*)d_in[3];
  const float* dw1  = (const float*)d_in[4];
  const float* db1  = (const float*)d_in[5];
  const float* dw2  = (const float*)d_in[6];
  const float* db2  = (const float*)d_in[7];
  const float* dw3  = (const float*)d_in[8];
  const float* db3  = (const float*)d_in[9];
  const float* pnw0 = (const float*)d_in[10];
  const float* pnb0 = (const float*)d_in[11];
  const float* pnw1 = (const float*)d_in[12];
  const float* pnb1 = (const float*)d_in[13];
  const float* pnw2 = (const float*)d_in[14];
  const float* pnb2 = (const float*)d_in[15];
  float* out = (float*)d_out;

  unsigned short* pw = (unsigned short*)d_ws;
  unsigned short* pw0 = pw;
  unsigned short* pw1 = pw + 65536;
  unsigned short* pw2 = pw + 327680;
  unsigned short* pw3 = pw + 589824;
  float* traj = (float*)(pw + 598016);

  traj_pack_kernel<<<4673, 128, 0, stream>>>(pnw0, pnb0, pnw1, pnb1, pnw2, pnb2,
                                             dw0, dw1, dw2, dw3, pw, traj);
  decoder_kernel<<<B_TOTAL / MTILE, 512, 0, stream>>>(x, tauv, pw0, db0, pw1, db1,
                                                      pw2, db2, pw3, db3, traj, out);
}